// Round 5
// baseline (638.430 us; speedup 1.0000x reference)
//
#include <hip/hip_runtime.h>
#include <math.h>

#define D_MODEL    768
#define N_FEAT     32768
#define K_TOP      64
#define AUX_K      128
#define BATCH      1024
#define DEAD_AFTER 1000
#define AUX_COEFF  0.03125f
#define ROWCAP     1024

typedef unsigned short u16;
typedef unsigned long long u64;
typedef __attribute__((ext_vector_type(8))) short short8;
typedef __attribute__((ext_vector_type(4))) float f32x4;

__device__ __forceinline__ unsigned sortable(float f) {
    unsigned u = __float_as_uint(f);
    return u ^ ((unsigned)((int)u >> 31) | 0x80000000u);
}
__device__ __forceinline__ float unsortable(unsigned s) {
    unsigned u = (s & 0x80000000u) ? (s ^ 0x80000000u) : ~s;
    return __uint_as_float(u);
}
__device__ __forceinline__ u16 f2bf(float v) {          // RNE f32->bf16
    unsigned u = __float_as_uint(v);
    unsigned r = u + 0x7FFFu + ((u >> 16) & 1u);
    return (u16)(r >> 16);
}
__device__ __forceinline__ float bf2f(u16 u) {
    return __uint_as_float(((unsigned)u) << 16);
}
__device__ __forceinline__ void gll16(const u16* g, u16* l) {
    __builtin_amdgcn_global_load_lds(
        (const __attribute__((address_space(1))) unsigned*)g,
        (__attribute__((address_space(3))) unsigned*)l, 16, 0, 0);
}

// ---------------------------------------------------------------- prep
__global__ __launch_bounds__(256) void k_prep(
    const float* __restrict__ x, const float* __restrict__ b_pre,
    const float* __restrict__ b_post, const float* __restrict__ avg,
    float* __restrict__ xn, float* __restrict__ enc_in,
    u16* __restrict__ Ah, float* __restrict__ sigma) {
    const int b = blockIdx.x, t = threadIdx.x;
    __shared__ float red[4];
    const float s = sqrtf((float)D_MODEL) / avg[0];
    float ss = 0.f;
#pragma unroll
    for (int c = 0; c < 3; c++) {
        int d = t + 256 * c;
        size_t i = (size_t)b * D_MODEL + d;
        float v = x[i] * s;
        xn[i] = v;
        float e = v - b_post[d] + b_pre[d];
        enc_in[i] = e;
        Ah[i] = f2bf(e);
        ss += e * e;
    }
    for (int o = 32; o > 0; o >>= 1) ss += __shfl_down(ss, o, 64);
    if ((t & 63) == 0) red[t >> 6] = ss;
    __syncthreads();
    if (t == 0) sigma[b] = sqrtf((red[0] + red[1] + red[2] + red[3]) / (float)D_MODEL);
}

// ---------------------------------------------------------------- dead mask
__global__ __launch_bounds__(256) void k_dead(
    const int* __restrict__ act, u64* __restrict__ dmask, float* __restrict__ scal) {
    int f = blockIdx.x * 256 + threadIdx.x;
    bool dead = act[f] > DEAD_AFTER;
    u64 m = __ballot(dead);
    if ((threadIdx.x & 63) == 0) {
        dmask[f >> 6] = m;
        if (m != 0ULL) scal[2] = 1.0f;   // benign race
    }
}

// ---------------------------------------------------------------- W_enc -> Bt hi/lo
__global__ __launch_bounds__(256) void k_convB(
    const float* __restrict__ W, u16* __restrict__ Bh, u16* __restrict__ Bl) {
    __shared__ float tile[64][65];
    const int bx = blockIdx.x;
    const int by = blockIdx.y;
    const int tx = threadIdx.x & 63;
    const int ty = threadIdx.x >> 6;
#pragma unroll
    for (int it = 0; it < 16; it++) {
        int k = ty + it * 4;
        tile[k][tx] = W[(size_t)(by * 64 + k) * N_FEAT + bx * 64 + tx];
    }
    __syncthreads();
    const int n  = threadIdx.x >> 2;
    const int kg = threadIdx.x & 3;
    u16 h[16], lo[16];
#pragma unroll
    for (int i = 0; i < 16; i++) {
        float v = tile[kg * 16 + i][n];
        h[i]  = f2bf(v);
        lo[i] = f2bf(v - bf2f(h[i]));
    }
    size_t off = (size_t)(bx * 64 + n) * D_MODEL + by * 64 + kg * 16;
    *(short8*)&Bh[off]     = *(short8*)&h[0];
    *(short8*)&Bh[off + 8] = *(short8*)&h[8];
    *(short8*)&Bl[off]     = *(short8*)&lo[0];
    *(short8*)&Bl[off + 8] = *(short8*)&lo[8];
}

// ---------------------------------------------------------------- bf16 MFMA GEMM + fused scan
// m97-style: BK=64, single 32KB LDS buffer, 2 barriers/step, 12 steps.
// Swizzled chunk map chunk(m,kq)=m*8+((kq+(m>>1))&7): staging stays fully
// coalesced (8 lanes = one 128B row) and frag reads spread over all 8
// bank-groups (kills the r4 SQ_LDS_BANK_CONFLICT).
__global__ __launch_bounds__(256) void k_gemm(
    const u16* __restrict__ Ah, const u16* __restrict__ Bh,
    const float* __restrict__ sigma, const u64* __restrict__ dmask,
    u64* __restrict__ cand0, int* __restrict__ cnt0,
    u64* __restrict__ cand1, int* __restrict__ cnt1) {
    __shared__ __align__(16) u16 lds[16384];   // A 16KB + B 16KB
    const int l  = blockIdx.x;
    const int nx = (l & 7) + ((l >> 6) << 3);  // XCD swizzle
    const int my = (l >> 3) & 7;
    const int t  = threadIdx.x;
    const int w  = t >> 6, lane = t & 63;
    const int wm = w >> 1, wn = w & 1;
    const int lane15 = lane & 15, quad = lane >> 4;

    // staging: instr ci stages rows ci*32..+31; thread t -> row ci*32+(t>>3),
    // k-eighth skq; LDS chunk ci*256+t.
    const int sm  = t >> 3;
    const int skq = ((t & 7) - ((t >> 4) & 7)) & 7;
    const u16* pA = Ah + (size_t)(my * 128 + sm) * D_MODEL + skq * 8;
    const u16* pB = Bh + (size_t)(nx * 128 + sm) * D_MODEL + skq * 8;
    u16* lA = lds + t * 8;
    u16* lB = lds + 8192 + t * 8;

    auto stage = [&](int k0) {
#pragma unroll
        for (int ci = 0; ci < 4; ci++) {
            gll16(pA + (size_t)ci * 32 * D_MODEL + k0, lA + ci * 2048);
            gll16(pB + (size_t)ci * 32 * D_MODEL + k0, lB + ci * 2048);
        }
    };

    f32x4 acc[4][4];
#pragma unroll
    for (int i = 0; i < 4; i++)
#pragma unroll
        for (int j = 0; j < 4; j++) acc[i][j] = (f32x4){0.f, 0.f, 0.f, 0.f};

    for (int ks = 0; ks < D_MODEL / 64; ks++) {
        __syncthreads();                 // readers of previous tile done
        stage(ks * 64);
        __syncthreads();                 // vmcnt(0) drain: staged data visible
#pragma unroll
        for (int s = 0; s < 2; s++) {
            short8 a[4], bf[4];
#pragma unroll
            for (int i = 0; i < 4; i++) {
                int m = wm * 64 + i * 16 + lane15;
                a[i] = *(const short8*)&lds[m * 64 + (((s << 2) + quad + (m >> 1)) & 7) * 8];
            }
#pragma unroll
            for (int j = 0; j < 4; j++) {
                int n = wn * 64 + j * 16 + lane15;
                bf[j] = *(const short8*)&lds[8192 + n * 64 + (((s << 2) + quad + (n >> 1)) & 7) * 8];
            }
#pragma unroll
            for (int i = 0; i < 4; i++)
#pragma unroll
                for (int j = 0; j < 4; j++)
                    acc[i][j] = __builtin_amdgcn_mfma_f32_16x16x32_bf16(a[i], bf[j], acc[i][j], 0, 0, 0);
        }
    }
    // ---- epilogue: threshold scan
    __syncthreads();
    float* srow = (float*)lds;
    u64*   sdw  = (u64*)&lds[256];
    if (t < 128) srow[t] = sigma[my * 128 + t];
    if (t == 128) sdw[0] = dmask[nx * 2];
    if (t == 129) sdw[1] = dmask[nx * 2 + 1];
    __syncthreads();
#pragma unroll
    for (int i = 0; i < 4; i++)
#pragma unroll
        for (int j = 0; j < 4; j++)
#pragma unroll
            for (int r = 0; r < 4; r++) {
                int rl = wm * 64 + i * 16 + quad * 4 + r;
                int cl = wn * 64 + j * 16 + lane15;
                float v = acc[i][j][r];
                float sg = srow[rl];
                if (v > 2.0f * sg) {
                    int grow = my * 128 + rl;
                    unsigned gcol = (unsigned)(nx * 128 + cl);
                    u64 key = ((u64)sortable(v) << 32) | (u64)(0xFFFFFFFFu - gcol);
                    if (v > 2.4f * sg) {
                        int p = atomicAdd(&cnt0[grow], 1);
                        if (p < ROWCAP) cand0[(size_t)grow * ROWCAP + p] = key;
                    }
                    if ((sdw[cl >> 6] >> (cl & 63)) & 1ULL) {
                        int p = atomicAdd(&cnt1[grow], 1);
                        if (p < ROWCAP) cand1[(size_t)grow * ROWCAP + p] = key;
                    }
                }
            }
}

// ---------------------------------------------------------------- topk: one sort + band rescue, no re-sort
__device__ __forceinline__ void bitonic(u64* sbuf, int ns, int t) {
    for (int size = 2; size <= ns; size <<= 1) {
        for (int stride = size >> 1; stride > 0; stride >>= 1) {
            for (int i = t; i < ns; i += 256) {
                int j = i ^ stride;
                if (j > i) {
                    u64 x0 = sbuf[i], x1 = sbuf[j];
                    bool up = ((i & size) == 0);
                    if ((x0 > x1) == up) { sbuf[i] = x1; sbuf[j] = x0; }
                }
            }
            __syncthreads();
        }
    }
}

__global__ __launch_bounds__(256) void k_topk(
    const u64* __restrict__ cand0, const int* __restrict__ cnt0,
    const u64* __restrict__ cand1, const int* __restrict__ cnt1,
    const float* __restrict__ enc_in, const float* __restrict__ W_enc,
    const u16* __restrict__ Bth, const u16* __restrict__ Btl,
    const float* __restrict__ sigma,
    int* __restrict__ tidx, float* __restrict__ tw,
    int* __restrict__ aidx, float* __restrict__ aw) {
    const int b = blockIdx.x, t = threadIdx.x;
    const int w = t >> 6, lane = t & 63;
    __shared__ u64 sbuf[ROWCAP];
    __shared__ float bandv[64];
    __shared__ int bandi[64];
    __shared__ int s_lo, s_hi;
    const float delta = 0.0125f * sigma[b];   // ~8 sigma of bf16 ranking error

    for (int p = 0; p < 2; p++) {
        const int k = p ? AUX_K : K_TOP;
        const u64* cand = p ? cand1 : cand0;
        int cnt = min(p ? cnt1[b] : cnt0[b], ROWCAP);
        int ns = k; while (ns < cnt) ns <<= 1;
        for (int i = t; i < ns; i += 256) sbuf[i] = (i < cnt) ? cand[(size_t)b * ROWCAP + i] : 0ULL;
        if (t == 0) { s_lo = ns; s_hi = -1; }
        __syncthreads();
        bitonic(sbuf, ns, t);   // ascending; top at the end
        int*   oidx = p ? aidx : tidx;
        float* ow   = p ? aw   : tw;
        if (cnt <= k) {          // block-uniform branch
            for (int i = t; i < k; i += 256) {
                float wv = 0.f; int fi = 0;
                if (i < cnt) {
                    u64 e = sbuf[ns - 1 - i];
                    wv = unsortable((unsigned)(e >> 32));
                    fi = (int)(0xFFFFFFFFu - (unsigned)(e & 0xFFFFFFFFull));
                }
                ow[(size_t)b * k + i] = wv;
                oidx[(size_t)b * k + i] = fi;
            }
            __syncthreads();
            continue;
        }
        // band around approx rank-k value (contiguous in sorted order)
        float vk = unsortable((unsigned)(sbuf[ns - k] >> 32));
        for (int i = t; i < ns; i += 256) {
            float v = unsortable((unsigned)(sbuf[i] >> 32));  // pads -> NaN -> excluded
            if (fabsf(v - vk) <= delta) { atomicMin(&s_lo, i); atomicMax(&s_hi, i); }
        }
        __syncthreads();
        int lo = s_lo, hi = s_hi;            // vk's position is in band -> hi >= ns-k
        if (hi - lo >= 64) lo = hi - 63;     // cap (astronomically rare)
        int bandn = hi - lo + 1;
        int above = ns - 1 - hi;             // guaranteed in-set, approx weights
        int r = k - above; if (r > bandn) r = bandn; if (r > 64) r = 64;
        for (int i = t; i < above; i += 256) {
            u64 e = sbuf[ns - 1 - i];
            ow[(size_t)b * k + i] = unsortable((unsigned)(e >> 32));
            oidx[(size_t)b * k + i] = (int)(0xFFFFFFFFu - (unsigned)(e & 0xFFFFFFFFull));
        }
        // recompute band values (p0: exact f32; p1: hi+lo bf16), wave-parallel
        for (int c = w; c < bandn; c += 4) {
            u64 e = sbuf[lo + c];
            unsigned fi = 0xFFFFFFFFu - (unsigned)(e & 0xFFFFFFFFull);
            float s = 0.f;
            if (p == 0) {
#pragma unroll
                for (int rr = 0; rr < 12; rr++) {
                    int d = lane + 64 * rr;
                    s += enc_in[(size_t)b * D_MODEL + d] * W_enc[(size_t)d * N_FEAT + fi];
                }
            } else {
#pragma unroll
                for (int rr = 0; rr < 12; rr++) {
                    int d = lane + 64 * rr;
                    s += enc_in[(size_t)b * D_MODEL + d] *
                         (bf2f(Bth[(size_t)fi * D_MODEL + d]) + bf2f(Btl[(size_t)fi * D_MODEL + d]));
                }
            }
            for (int o = 32; o > 0; o >>= 1) s += __shfl_down(s, o, 64);
            if (lane == 0) { bandv[c] = s; bandi[c] = (int)fi; }
        }
        __syncthreads();
        // wave 0: 64-lane bitonic (ascending) over band, write top r
        if (w == 0) {
            float key = (lane < bandn) ? bandv[lane] : -INFINITY;
            int   pay = (lane < bandn) ? bandi[lane] : 0;
#pragma unroll
            for (int kk = 2; kk <= 64; kk <<= 1)
#pragma unroll
                for (int j = kk >> 1; j > 0; j >>= 1) {
                    float ok = __shfl_xor(key, j, 64);
                    int   op = __shfl_xor(pay, j, 64);
                    bool lower = ((lane & j) == 0);
                    bool asc   = ((lane & kk) == 0);
                    bool keepmin = (lower == asc);
                    bool take = keepmin ? (ok < key) : (ok > key);
                    if (take) { key = ok; pay = op; }
                }
            if (lane >= 64 - r) {
                int slot = above + (lane - (64 - r));
                ow[(size_t)b * k + slot] = key;
                oidx[(size_t)b * k + slot] = pay;
            }
        }
        // safety fill (only reachable in impossible clamp cases)
        for (int i = t; i < k - above - r; i += 256) {
            u64 e = sbuf[lo - 1 - i];
            ow[(size_t)b * k + above + r + i] = unsortable((unsigned)(e >> 32));
            oidx[(size_t)b * k + above + r + i] = (int)(0xFFFFFFFFu - (unsigned)(e & 0xFFFFFFFFull));
        }
        __syncthreads();
    }
}

// ---------------------------------------------------------------- decode (f32 W_dec) + losses
__global__ __launch_bounds__(384) void k_decode(
    const float* __restrict__ Wd, const float* __restrict__ xn,
    const int* __restrict__ tidx, const float* __restrict__ tw,
    const int* __restrict__ aidx, const float* __restrict__ aw,
    const float* __restrict__ b_post, const float* __restrict__ avg,
    float* __restrict__ scal,
    float* __restrict__ y, float* __restrict__ loss) {
    const int b = blockIdx.x, t = threadIdx.x;
    __shared__ float sw[K_TOP];   __shared__ int sidx[K_TOP];
    __shared__ float saw[AUX_K];  __shared__ int saidx[AUX_K];
    __shared__ float red1[6], red2[6], red3[6];
    if (t < K_TOP) { sw[t] = tw[(size_t)b * K_TOP + t]; sidx[t] = tidx[(size_t)b * K_TOP + t]; }
    else if (t < K_TOP + AUX_K) {
        int j = t - K_TOP;
        saw[j] = aw[(size_t)b * AUX_K + j]; saidx[j] = aidx[(size_t)b * AUX_K + j];
    }
    __syncthreads();
    const float inv = avg[0] / sqrtf((float)D_MODEL);
    float rsum = 0.f, asum = 0.f, xsum = 0.f;
#pragma unroll
    for (int c = 0; c < 2; c++) {
        const int d = t + 384 * c;
        float acc = 0.f;
#pragma unroll 8
        for (int j = 0; j < K_TOP; j++)
            acc = fmaf(sw[j], Wd[(size_t)sidx[j] * D_MODEL + d], acc);
        float yn = acc + b_post[d];
        float aacc = 0.f;
#pragma unroll 8
        for (int j = 0; j < AUX_K; j++)
            aacc = fmaf(saw[j], Wd[(size_t)saidx[j] * D_MODEL + d], aacc);
        float xv = xn[(size_t)b * D_MODEL + d];
        float r = xv - yn;
        rsum += r * r;
        float ar = yn - xv - aacc;
        asum += ar * ar;
        xsum += xv * xv;
        y[(size_t)b * D_MODEL + d] = yn * inv;
    }
    for (int o = 32; o > 0; o >>= 1) {
        rsum += __shfl_down(rsum, o, 64);
        asum += __shfl_down(asum, o, 64);
        xsum += __shfl_down(xsum, o, 64);
    }
    if ((t & 63) == 0) { int ww = t >> 6; red1[ww] = rsum; red2[ww] = asum; red3[ww] = xsum; }
    __syncthreads();
    if (t == 0) {
        float R = 0.f, A = 0.f, X = 0.f;
#pragma unroll
        for (int i = 0; i < 6; i++) { R += red1[i]; A += red2[i]; X += red3[i]; }
        loss[b] = R / (float)D_MODEL + AUX_COEFF * (scal[2] > 0.f ? A / (float)D_MODEL : 0.f);
        atomicAdd(&scal[0], R);
        atomicAdd(&scal[1], X);
    }
}

__global__ void k_fin(const float* __restrict__ scal, float* __restrict__ fvu_out) {
    *fvu_out = scal[0] / scal[1];
}

// ---------------------------------------------------------------- launch
extern "C" void kernel_launch(void* const* d_in, const int* in_sizes, int n_in,
                              void* d_out, int out_size, void* d_ws, size_t ws_size,
                              hipStream_t stream) {
    const float* x      = (const float*)d_in[0];
    const float* W_enc  = (const float*)d_in[1];
    const float* W_dec  = (const float*)d_in[2];
    const float* b_pre  = (const float*)d_in[3];
    const float* b_post = (const float*)d_in[4];
    const float* avg    = (const float*)d_in[5];
    const int*   act    = (const int*)d_in[6];

    char* base = (char*)d_ws;
    const size_t OFF_XN    = 0;
    const size_t OFF_ENCIN = 3145728;
    const size_t OFF_SIGMA = 6291456;
    const size_t OFF_AH    = 6295552;
    const size_t OFF_CNT0  = 7868416;
    const size_t OFF_CNT1  = 7872512;
    const size_t OFF_DMASK = 7876608;
    const size_t OFF_SCAL  = 7880704;
    const size_t OFF_TW    = 7880960;
    const size_t OFF_TIDX  = 8143104;
    const size_t OFF_AW    = 8405248;
    const size_t OFF_AIDX  = 8929536;
    const size_t OFF_CAND0 = 9453824;
    const size_t OFF_CAND1 = 17842432;
    const size_t OFF_BTH   = 26231040;
    const size_t OFF_BTL   = 76562688;

    float* xn     = (float*)(base + OFF_XN);
    float* enc_in = (float*)(base + OFF_ENCIN);
    float* sigma  = (float*)(base + OFF_SIGMA);
    u16*   Ah     = (u16*)(base + OFF_AH);
    int*   cnt0   = (int*)(base + OFF_CNT0);
    int*   cnt1   = (int*)(base + OFF_CNT1);
    u64*   dmask  = (u64*)(base + OFF_DMASK);
    float* scal   = (float*)(base + OFF_SCAL);
    float* tw     = (float*)(base + OFF_TW);
    int*   tidx   = (int*)(base + OFF_TIDX);
    float* aw     = (float*)(base + OFF_AW);
    int*   aidx   = (int*)(base + OFF_AIDX);
    u64*   cand0  = (u64*)(base + OFF_CAND0);
    u64*   cand1  = (u64*)(base + OFF_CAND1);
    u16*   Bth    = (u16*)(base + OFF_BTH);
    u16*   Btl    = (u16*)(base + OFF_BTL);

    float* y    = (float*)d_out;
    float* loss = y + (size_t)BATCH * D_MODEL;
    float* fvu  = loss + BATCH;

    hipMemsetAsync(base + OFF_CNT0, 0, 12544, stream);  // cnt0+cnt1+dmask+scal

    k_prep<<<BATCH, 256, 0, stream>>>(x, b_pre, b_post, avg, xn, enc_in, Ah, sigma);
    k_dead<<<N_FEAT / 256, 256, 0, stream>>>(act, dmask, scal);
    k_convB<<<dim3(N_FEAT / 64, D_MODEL / 64), 256, 0, stream>>>(W_enc, Bth, Btl);
    k_gemm<<<(N_FEAT / 128) * (BATCH / 128), 256, 0, stream>>>(
        Ah, Bth, sigma, dmask, cand0, cnt0, cand1, cnt1);
    k_topk<<<BATCH, 256, 0, stream>>>(cand0, cnt0, cand1, cnt1, enc_in, W_enc, Bth, Btl,
                                      sigma, tidx, tw, aidx, aw);
    k_decode<<<BATCH, 384, 0, stream>>>(W_dec, xn, tidx, tw, aidx, aw, b_post, avg, scal, y, loss);
    k_fin<<<1, 1, 0, stream>>>(scal, fvu);
}